// Round 3
// baseline (1411.208 us; speedup 1.0000x reference)
//
#include <hip/hip_runtime.h>
#include <cstdint>
#include <cstddef>

#define N_NODES 50000
#define N_EDGES 800000
#define IN_DIM 256
#define HID 256
#define EMB 64

// ---------------------------------------------------------------------------
// CSR build: histogram of dst -> exclusive scan -> fill sorted src list
// ---------------------------------------------------------------------------
__global__ void hist_kernel(const int* __restrict__ dst, int* __restrict__ cnt, int E) {
    int e = blockIdx.x * blockDim.x + threadIdx.x;
    if (e < E) atomicAdd(&cnt[dst[e]], 1);
}

// Single-block exclusive scan over n counts. offs[0..n]; cursor copy for fill.
__global__ void scan_kernel(const int* __restrict__ cnt, int* __restrict__ offs,
                            int* __restrict__ cursor, int n) {
    __shared__ int buf[1024];
    __shared__ int carry_s;
    int tid = threadIdx.x;
    if (tid == 0) carry_s = 0;
    __syncthreads();
    for (int base = 0; base < n; base += 1024) {
        int i = base + tid;
        int v = (i < n) ? cnt[i] : 0;
        buf[tid] = v;
        __syncthreads();
        #pragma unroll
        for (int off = 1; off < 1024; off <<= 1) {
            int t = (tid >= off) ? buf[tid - off] : 0;
            __syncthreads();
            buf[tid] += t;
            __syncthreads();
        }
        int excl = buf[tid] - v + carry_s;
        if (i < n) { offs[i] = excl; cursor[i] = excl; }
        __syncthreads();                    // everyone has read carry_s
        if (tid == 1023) carry_s += buf[1023];
        __syncthreads();
    }
    if (tid == 0) offs[n] = carry_s;
}

__global__ void fill_kernel(const int* __restrict__ src, const int* __restrict__ dst,
                            int* __restrict__ cursor, int* __restrict__ ssrc, int E) {
    int e = blockIdx.x * blockDim.x + threadIdx.x;
    if (e < E) {
        int d = dst[e];
        int pos = atomicAdd(&cursor[d], 1);
        ssrc[pos] = src[e];
    }
}

// ---------------------------------------------------------------------------
// Wide layer-1 GEMM: g1[:, by*128 : by*128+128] = A @ colblock(B)
// A:[M,256] rm. B1,B2:[256,256] rm; by in 0..3 -> {B1 cols 0/128, B2 cols 0/128}.
// g1 row stride 512. 128x128 tile, 256 threads, 2x2x(4x4) micro-tile, BK=16.
// No bias / no relu here (folded into combine1).
// ---------------------------------------------------------------------------
__global__ __launch_bounds__(256) void gemm_wide_128(
        const float* __restrict__ A, const float* __restrict__ B1,
        const float* __restrict__ B2, float* __restrict__ C, int M) {
    __shared__ float As[16][128];   // [k][m]
    __shared__ float Bs[16][128];   // [k][n]

    int tid = threadIdx.x;
    int tx = tid & 15;              // col group
    int ty = tid >> 4;              // row group
    int rowBase = blockIdx.x * 128;
    int by = blockIdx.y;            // 0..3
    const float* B = (by < 2) ? B1 : B2;
    int colSel = (by & 1) * 128;    // column block within B

    int ar = tid >> 1;              // 0..127 (A row within tile)
    int ak = (tid & 1) * 8;         // 0 or 8 (A k-offset)
    int br = tid >> 4;              // 0..15  (B k-row)
    int bc = (tid & 15) * 4;        // 0..60  (B col)

    float acc[2][2][4][4] = {};

    for (int k0 = 0; k0 < 256; k0 += 16) {
        int gr = rowBase + ar;
        float4 a0 = make_float4(0.f, 0.f, 0.f, 0.f);
        float4 a1 = make_float4(0.f, 0.f, 0.f, 0.f);
        if (gr < M) {
            const float* ap = A + (size_t)gr * 256 + k0 + ak;
            a0 = *(const float4*)(ap);
            a1 = *(const float4*)(ap + 4);
        }
        As[ak + 0][ar] = a0.x; As[ak + 1][ar] = a0.y;
        As[ak + 2][ar] = a0.z; As[ak + 3][ar] = a0.w;
        As[ak + 4][ar] = a1.x; As[ak + 5][ar] = a1.y;
        As[ak + 6][ar] = a1.z; As[ak + 7][ar] = a1.w;
        const float* bp = B + (size_t)(k0 + br) * 256 + colSel + bc;
        *(float4*)&Bs[br][bc]      = *(const float4*)(bp);
        *(float4*)&Bs[br][bc + 64] = *(const float4*)(bp + 64);
        __syncthreads();
        #pragma unroll
        for (int k = 0; k < 16; ++k) {
            float a[8], b[8];
            *(float4*)&a[0] = *(const float4*)&As[k][ty * 4];
            *(float4*)&a[4] = *(const float4*)&As[k][64 + ty * 4];
            *(float4*)&b[0] = *(const float4*)&Bs[k][tx * 4];
            *(float4*)&b[4] = *(const float4*)&Bs[k][64 + tx * 4];
            #pragma unroll
            for (int i2 = 0; i2 < 2; ++i2)
                #pragma unroll
                for (int i = 0; i < 4; ++i)
                    #pragma unroll
                    for (int j2 = 0; j2 < 2; ++j2)
                        #pragma unroll
                        for (int j = 0; j < 4; ++j)
                            acc[i2][j2][i][j] += a[i2 * 4 + i] * b[j2 * 4 + j];
        }
        __syncthreads();
    }

    #pragma unroll
    for (int i2 = 0; i2 < 2; ++i2) {
        #pragma unroll
        for (int i = 0; i < 4; ++i) {
            int gr = rowBase + i2 * 64 + ty * 4 + i;
            if (gr < M) {
                #pragma unroll
                for (int j2 = 0; j2 < 2; ++j2) {
                    float4 v;
                    v.x = acc[i2][j2][i][0];
                    v.y = acc[i2][j2][i][1];
                    v.z = acc[i2][j2][i][2];
                    v.w = acc[i2][j2][i][3];
                    *(float4*)(C + (size_t)gr * 512 + by * 128 + j2 * 64 + tx * 4) = v;
                }
            }
        }
    }
}

// ---------------------------------------------------------------------------
// Layer-2 concat GEMM: g2[:, by*64 : by*64+64] = A @ (by ? W2r : W2n)
// A:[M,256] rm. B:[256,64] rm. g2 row stride = 128. 128x64 tile, 256 threads.
// No bias (folded into combine2).
// ---------------------------------------------------------------------------
__global__ __launch_bounds__(256) void gemm_cat_64(
        const float* __restrict__ A, const float* __restrict__ B1,
        const float* __restrict__ B2, float* __restrict__ C, int M) {
    __shared__ float As[16][128];
    __shared__ float Bs[16][64];

    int tid = threadIdx.x;
    int tx = tid & 15;
    int ty = tid >> 4;
    int rowBase = blockIdx.x * 128;
    int by = blockIdx.y;                 // 0 -> W2n half, 1 -> W2r half
    const float* B = by ? B2 : B1;

    int ar = tid >> 1;                   // 0..127
    int ak = (tid & 1) * 8;
    int br = tid >> 4;                   // 0..15
    int bc = (tid & 15) * 4;             // 0..60

    float acc[2][4][4] = {};

    for (int k0 = 0; k0 < 256; k0 += 16) {
        int gr = rowBase + ar;
        float4 a0 = make_float4(0.f, 0.f, 0.f, 0.f);
        float4 a1 = make_float4(0.f, 0.f, 0.f, 0.f);
        if (gr < M) {
            const float* ap = A + (size_t)gr * 256 + k0 + ak;
            a0 = *(const float4*)(ap);
            a1 = *(const float4*)(ap + 4);
        }
        As[ak + 0][ar] = a0.x; As[ak + 1][ar] = a0.y;
        As[ak + 2][ar] = a0.z; As[ak + 3][ar] = a0.w;
        As[ak + 4][ar] = a1.x; As[ak + 5][ar] = a1.y;
        As[ak + 6][ar] = a1.z; As[ak + 7][ar] = a1.w;
        *(float4*)&Bs[br][bc] = *(const float4*)(B + (size_t)(k0 + br) * 64 + bc);
        __syncthreads();
        #pragma unroll
        for (int k = 0; k < 16; ++k) {
            float a[8], b[4];
            *(float4*)&a[0] = *(const float4*)&As[k][ty * 4];
            *(float4*)&a[4] = *(const float4*)&As[k][64 + ty * 4];
            *(float4*)&b[0] = *(const float4*)&Bs[k][tx * 4];
            #pragma unroll
            for (int i2 = 0; i2 < 2; ++i2)
                #pragma unroll
                for (int i = 0; i < 4; ++i)
                    #pragma unroll
                    for (int j = 0; j < 4; ++j)
                        acc[i2][i][j] += a[i2 * 4 + i] * b[j];
        }
        __syncthreads();
    }

    #pragma unroll
    for (int i2 = 0; i2 < 2; ++i2) {
        #pragma unroll
        for (int i = 0; i < 4; ++i) {
            int gr = rowBase + i2 * 64 + ty * 4 + i;
            if (gr < M) {
                float4 v;
                v.x = acc[i2][i][0];
                v.y = acc[i2][i][1];
                v.z = acc[i2][i][2];
                v.w = acc[i2][i][3];
                *(float4*)(C + (size_t)gr * 128 + by * 64 + tx * 4) = v;
            }
        }
    }
}

// ---------------------------------------------------------------------------
// combine1: h[i] = relu( segsum(t1)[i]/max(deg,1) + r1[i] + b1 )
// g1:[N,512] = [t1 | r1] (128 float4/row: t1 = f4 0..63, r1 = f4 64..127).
// One wave per node, float4 per lane. 2-deep unrolled gather for ILP.
// ---------------------------------------------------------------------------
__global__ void combine1_kernel(const float* __restrict__ g1,
                                const int* __restrict__ offs,
                                const int* __restrict__ ssrc,
                                const float* __restrict__ b1,
                                float* __restrict__ h, int n) {
    int gtid = blockIdx.x * blockDim.x + threadIdx.x;
    int node = gtid >> 6;
    int lane = gtid & 63;
    if (node >= n) return;
    int beg = offs[node];
    int end = offs[node + 1];
    const float4* g = (const float4*)g1;     // row stride = 128 float4
    float4 s = make_float4(0.f, 0.f, 0.f, 0.f);
    int e = beg;
    for (; e + 1 < end; e += 2) {
        int s0 = ssrc[e];
        int s1 = ssrc[e + 1];
        float4 v0 = g[(size_t)s0 * 128 + lane];
        float4 v1 = g[(size_t)s1 * 128 + lane];
        s.x += v0.x + v1.x; s.y += v0.y + v1.y;
        s.z += v0.z + v1.z; s.w += v0.w + v1.w;
    }
    if (e < end) {
        int s0 = ssrc[e];
        float4 v0 = g[(size_t)s0 * 128 + lane];
        s.x += v0.x; s.y += v0.y; s.z += v0.z; s.w += v0.w;
    }
    int deg = end - beg;
    float inv = 1.0f / (float)(deg > 0 ? deg : 1);
    float4 r = g[(size_t)node * 128 + 64 + lane];
    float4 bb = ((const float4*)b1)[lane];
    float4 o;
    o.x = s.x * inv + r.x + bb.x;
    o.y = s.y * inv + r.y + bb.y;
    o.z = s.z * inv + r.z + bb.z;
    o.w = s.w * inv + r.w + bb.w;
    o.x = o.x > 0.f ? o.x : 0.f;
    o.y = o.y > 0.f ? o.y : 0.f;
    o.z = o.z > 0.f ? o.z : 0.f;
    o.w = o.w > 0.f ? o.w : 0.f;
    ((float4*)h)[(size_t)node * 64 + lane] = o;
}

// ---------------------------------------------------------------------------
// combine2: emb[i][c] = segsum(t2)[i][c]/max(deg,1) + r2[i][c] + b2[c]
// g2:[N,128] = [t2 | r2]. One wave per node, scalar lane per channel (c=0..63).
// ---------------------------------------------------------------------------
__global__ void combine2_kernel(const float* __restrict__ g2,
                                const int* __restrict__ offs,
                                const int* __restrict__ ssrc,
                                const float* __restrict__ b2,
                                float* __restrict__ emb, int n) {
    int gtid = blockIdx.x * blockDim.x + threadIdx.x;
    int node = gtid >> 6;
    int lane = gtid & 63;
    if (node >= n) return;
    int beg = offs[node];
    int end = offs[node + 1];
    float s = 0.f;
    int e = beg;
    for (; e + 1 < end; e += 2) {
        int s0 = ssrc[e];
        int s1 = ssrc[e + 1];
        float v0 = g2[(size_t)s0 * 128 + lane];
        float v1 = g2[(size_t)s1 * 128 + lane];
        s += v0 + v1;
    }
    if (e < end) s += g2[(size_t)ssrc[e] * 128 + lane];
    int deg = end - beg;
    float inv = 1.0f / (float)(deg > 0 ? deg : 1);
    emb[(size_t)node * 64 + lane] =
        s * inv + g2[(size_t)node * 128 + 64 + lane] + b2[lane];
}

// ---------------------------------------------------------------------------
// Head: out[i] = sigmoid( dot(emb_u[i], W[0:64]) + dot(emb_i[i], W[64:128]) + b )
// ---------------------------------------------------------------------------
__global__ void head_kernel(const float* __restrict__ eu, const float* __restrict__ ei,
                            const float* __restrict__ hW, const float* __restrict__ hb,
                            float* __restrict__ out, int n) {
    __shared__ float w[128];
    __shared__ float b0;
    if (threadIdx.x < 128) w[threadIdx.x] = hW[threadIdx.x];
    if (threadIdx.x == 0) b0 = hb[0];
    __syncthreads();
    int i = blockIdx.x * blockDim.x + threadIdx.x;
    if (i >= n) return;
    const float4* a = (const float4*)(eu + (size_t)i * 64);
    const float4* c = (const float4*)(ei + (size_t)i * 64);
    float s = b0;
    #pragma unroll
    for (int j = 0; j < 16; ++j) {
        float4 v = a[j];
        s += v.x * w[j * 4 + 0] + v.y * w[j * 4 + 1] + v.z * w[j * 4 + 2] + v.w * w[j * 4 + 3];
    }
    #pragma unroll
    for (int j = 0; j < 16; ++j) {
        float4 v = c[j];
        s += v.x * w[64 + j * 4 + 0] + v.y * w[64 + j * 4 + 1] + v.z * w[64 + j * 4 + 2] + v.w * w[64 + j * 4 + 3];
    }
    out[i] = 1.0f / (1.0f + __expf(-s));
}

// ---------------------------------------------------------------------------
extern "C" void kernel_launch(void* const* d_in, const int* in_sizes, int n_in,
                              void* d_out, int out_size, void* d_ws, size_t ws_size,
                              hipStream_t stream) {
    const float* user_x = (const float*)d_in[0];
    const float* item_x = (const float*)d_in[1];
    const int*   u_ei   = (const int*)d_in[2];
    const int*   i_ei   = (const int*)d_in[3];
    const float* u1_Wn = (const float*)d_in[4];
    const float* u1_Wr = (const float*)d_in[5];
    const float* u1_b  = (const float*)d_in[6];
    const float* u2_Wn = (const float*)d_in[7];
    const float* u2_Wr = (const float*)d_in[8];
    const float* u2_b  = (const float*)d_in[9];
    const float* i1_Wn = (const float*)d_in[10];
    const float* i1_Wr = (const float*)d_in[11];
    const float* i1_b  = (const float*)d_in[12];
    const float* i2_Wn = (const float*)d_in[13];
    const float* i2_Wr = (const float*)d_in[14];
    const float* i2_b  = (const float*)d_in[15];
    const float* head_W = (const float*)d_in[16];
    const float* head_b = (const float*)d_in[17];
    float* out = (float*)d_out;

    // Workspace carve-up (256B aligned). Total ~230 MB.
    char* p = (char*)d_ws;
    auto alloc = [&](size_t bytes) -> void* {
        void* r = (void*)p;
        p += (bytes + 255) & ~(size_t)255;
        return r;
    };
    int* cnt_u  = (int*)alloc((size_t)N_NODES * 4);
    int* cnt_i  = (int*)alloc((size_t)N_NODES * 4);
    int* offs_u = (int*)alloc((size_t)(N_NODES + 1) * 4);
    int* offs_i = (int*)alloc((size_t)(N_NODES + 1) * 4);
    int* cur_u  = (int*)alloc((size_t)N_NODES * 4);
    int* cur_i  = (int*)alloc((size_t)N_NODES * 4);
    int* ssrc_u = (int*)alloc((size_t)N_EDGES * 4);
    int* ssrc_i = (int*)alloc((size_t)N_EDGES * 4);
    float* g1    = (float*)alloc((size_t)N_NODES * 512 * 4);  // [t1 | r1]
    float* hbuf  = (float*)alloc((size_t)N_NODES * HID * 4);  // h
    float* g2    = (float*)alloc((size_t)N_NODES * 128 * 4);  // [t2 | r2]
    float* emb_u = (float*)alloc((size_t)N_NODES * EMB * 4);
    float* emb_i = (float*)alloc((size_t)N_NODES * EMB * 4);

    hipMemsetAsync(cnt_u, 0, (size_t)N_NODES * 4, stream);
    hipMemsetAsync(cnt_i, 0, (size_t)N_NODES * 4, stream);

    const int* u_src = u_ei;
    const int* u_dst = u_ei + N_EDGES;
    const int* i_src = i_ei;
    const int* i_dst = i_ei + N_EDGES;

    int egrid = (N_EDGES + 255) / 256;
    int sgrid = (N_NODES * 64 + 255) / 256;        // one wave per node
    int mgrid128 = (N_NODES + 127) / 128;          // 391

    // --- CSR build, both graphs ---
    hist_kernel<<<egrid, 256, 0, stream>>>(u_dst, cnt_u, N_EDGES);
    hist_kernel<<<egrid, 256, 0, stream>>>(i_dst, cnt_i, N_EDGES);
    scan_kernel<<<1, 1024, 0, stream>>>(cnt_u, offs_u, cur_u, N_NODES);
    scan_kernel<<<1, 1024, 0, stream>>>(cnt_i, offs_i, cur_i, N_NODES);
    fill_kernel<<<egrid, 256, 0, stream>>>(u_src, u_dst, cur_u, ssrc_u, N_EDGES);
    fill_kernel<<<egrid, 256, 0, stream>>>(i_src, i_dst, cur_i, ssrc_i, N_EDGES);

    // --- user encoder ---
    {
        dim3 g(mgrid128, 4);   // Nout = 512
        gemm_wide_128<<<g, 256, 0, stream>>>(user_x, u1_Wn, u1_Wr, g1, N_NODES);
    }
    combine1_kernel<<<sgrid, 256, 0, stream>>>(g1, offs_u, ssrc_u, u1_b, hbuf, N_NODES);
    {
        dim3 g(mgrid128, 2);   // Nout = 128
        gemm_cat_64<<<g, 256, 0, stream>>>(hbuf, u2_Wn, u2_Wr, g2, N_NODES);
    }
    combine2_kernel<<<sgrid, 256, 0, stream>>>(g2, offs_u, ssrc_u, u2_b, emb_u, N_NODES);

    // --- item encoder ---
    {
        dim3 g(mgrid128, 4);
        gemm_wide_128<<<g, 256, 0, stream>>>(item_x, i1_Wn, i1_Wr, g1, N_NODES);
    }
    combine1_kernel<<<sgrid, 256, 0, stream>>>(g1, offs_i, ssrc_i, i1_b, hbuf, N_NODES);
    {
        dim3 g(mgrid128, 2);
        gemm_cat_64<<<g, 256, 0, stream>>>(hbuf, i2_Wn, i2_Wr, g2, N_NODES);
    }
    combine2_kernel<<<sgrid, 256, 0, stream>>>(g2, offs_i, ssrc_i, i2_b, emb_i, N_NODES);

    // --- scoring head ---
    head_kernel<<<(N_NODES + 255) / 256, 256, 0, stream>>>(emb_u, emb_i, head_W,
                                                           head_b, out, N_NODES);
}

// Round 5
// 1151.437 us; speedup vs baseline: 1.2256x; 1.2256x over previous
//
#include <hip/hip_runtime.h>
#include <cstdint>
#include <cstddef>

#define N_NODES 50000
#define N_EDGES 800000
#define IN_DIM 256
#define HID 256
#define EMB 64

typedef __attribute__((ext_vector_type(8))) short bf16x8v;   // 8 bf16 in 4 VGPRs
typedef __attribute__((ext_vector_type(4))) float f32x4v;    // MFMA accumulator

// ---- manual bf16 RNE convert (avoids header API variance) --------------------
__device__ inline ushort f2bf(float f) {
    uint32_t u = __float_as_uint(f);
    uint32_t r = (u + 0x7FFFu + ((u >> 16) & 1u)) >> 16;
    return (ushort)r;
}
__device__ inline float bf2f(ushort b) {
    return __uint_as_float((uint32_t)b << 16);
}

// ---------------------------------------------------------------------------
// CSR build: histogram of dst -> exclusive scan -> fill sorted src list
// ---------------------------------------------------------------------------
__global__ void hist_kernel(const int* __restrict__ dst, int* __restrict__ cnt, int E) {
    int e = blockIdx.x * blockDim.x + threadIdx.x;
    if (e < E) atomicAdd(&cnt[dst[e]], 1);
}

__global__ void scan_kernel(const int* __restrict__ cnt, int* __restrict__ offs,
                            int* __restrict__ cursor, int n) {
    __shared__ int buf[1024];
    __shared__ int carry_s;
    int tid = threadIdx.x;
    if (tid == 0) carry_s = 0;
    __syncthreads();
    for (int base = 0; base < n; base += 1024) {
        int i = base + tid;
        int v = (i < n) ? cnt[i] : 0;
        buf[tid] = v;
        __syncthreads();
        #pragma unroll
        for (int off = 1; off < 1024; off <<= 1) {
            int t = (tid >= off) ? buf[tid - off] : 0;
            __syncthreads();
            buf[tid] += t;
            __syncthreads();
        }
        int excl = buf[tid] - v + carry_s;
        if (i < n) { offs[i] = excl; cursor[i] = excl; }
        __syncthreads();
        if (tid == 1023) carry_s += buf[1023];
        __syncthreads();
    }
    if (tid == 0) offs[n] = carry_s;
}

__global__ void fill_kernel(const int* __restrict__ src, const int* __restrict__ dst,
                            int* __restrict__ cursor, int* __restrict__ ssrc, int E) {
    int e = blockIdx.x * blockDim.x + threadIdx.x;
    if (e < E) {
        int d = dst[e];
        int pos = atomicAdd(&cursor[d], 1);
        ssrc[pos] = src[e];
    }
}

// ---------------------------------------------------------------------------
// cvt_split: f32 [n] -> bf16 hi + bf16 lo (residual). One thread per 4 elems.
// ---------------------------------------------------------------------------
__global__ void cvt_split(const float* __restrict__ x, ushort* __restrict__ xh,
                          ushort* __restrict__ xl, int n4) {
    int i = blockIdx.x * blockDim.x + threadIdx.x;
    if (i >= n4) return;
    float4 v = ((const float4*)x)[i];
    ushort4 h, l;
    h.x = f2bf(v.x); l.x = f2bf(v.x - bf2f(h.x));
    h.y = f2bf(v.y); l.y = f2bf(v.y - bf2f(h.y));
    h.z = f2bf(v.z); l.z = f2bf(v.z - bf2f(h.z));
    h.w = f2bf(v.w); l.w = f2bf(v.w - bf2f(h.w));
    ((ushort4*)xh)[i] = h;
    ((ushort4*)xl)[i] = l;
}

// ---------------------------------------------------------------------------
// cvt_wT: build transposed+split weight BT[n][k] (k=256) from B1,B2 [256,Nhalf]
//   n < Nhalf -> B1 column n ; else B2 column n-Nhalf.  One thread per element.
// ---------------------------------------------------------------------------
__global__ void cvt_wT(const float* __restrict__ B1, const float* __restrict__ B2,
                       ushort* __restrict__ th, ushort* __restrict__ tl, int Nhalf) {
    int idx = blockIdx.x * blockDim.x + threadIdx.x;   // n*256 + k
    if (idx >= 2 * Nhalf * 256) return;
    int nn = idx >> 8;
    int k  = idx & 255;
    const float* Bp = (nn < Nhalf) ? B1 : B2;
    int col = (nn < Nhalf) ? nn : nn - Nhalf;
    float v = Bp[(size_t)k * Nhalf + col];
    ushort h = f2bf(v);
    th[idx] = h;
    tl[idx] = f2bf(v - bf2f(h));
}

// ---------------------------------------------------------------------------
// bf16x3 split MFMA GEMM:  C[M, ldc] (cols colBase..+128) = A @ BT^T
//   A   = Ah + Al : [M,256] bf16 row-major (hi/lo split of fp32 A)
//   BT  = BTh/BTl : [Ntot,256] bf16 row-major (transposed split weights)
//   C fp32, block tile 128x128, 4 waves (2x2), each wave 64x64 = 4x4 frags,
//   mfma_f32_16x16x32_bf16, 3 terms (hh, hl, lh). A staged in LDS with
//   slot ^= (row>>1)&3 XOR swizzle (conflict-free frag reads); B frags read
//   directly from global (<=512KB, L1/L2-hot).
// ---------------------------------------------------------------------------
__global__ __launch_bounds__(256) void gemm_bf16x3(
        const ushort* __restrict__ Ah, const ushort* __restrict__ Al,
        const ushort* __restrict__ BTh, const ushort* __restrict__ BTl,
        float* __restrict__ C, int M, int ldc) {
    __shared__ ushort As[2][128 * 32];   // [hi/lo][row*32 + k], 16 KiB

    int tid  = threadIdx.x;
    int lane = tid & 63;
    int wv   = tid >> 6;        // 0..3
    int wm   = wv >> 1;         // wave row
    int wn   = wv & 1;          // wave col
    int rowBase = blockIdx.x * 128;
    int colBase = blockIdx.y * 128;

    // staging map: thread t -> matrix (hi/lo) = t>>7, row = t&127, 4x16B each
    int sr = tid & 127;
    int sm = tid >> 7;
    const ushort* Ag = sm ? Al : Ah;
    int grow = rowBase + sr;
    bool rok = grow < M;
    int sxor = (sr >> 1) & 3;

    // fragment lane decomposition
    int fr = lane & 15;         // A row-in-frag / B col / C col
    int fc = lane >> 4;         // k-slot (8 elems each) / C row group
    int axor = (fr >> 1) & 3;   // read-side swizzle (row bits 1..2)

    f32x4v zero4 = {0.f, 0.f, 0.f, 0.f};
    f32x4v acc[4][4];
    #pragma unroll
    for (int a = 0; a < 4; ++a)
        #pragma unroll
        for (int b = 0; b < 4; ++b) acc[a][b] = zero4;

    for (int k0 = 0; k0 < 256; k0 += 32) {
        __syncthreads();                       // protect LDS from prior reads
        {
            const ushort* gs = Ag + (size_t)grow * 256 + k0;
            #pragma unroll
            for (int s = 0; s < 4; ++s) {
                uint4 v = rok ? *(const uint4*)(gs + s * 8) : make_uint4(0u, 0u, 0u, 0u);
                *(uint4*)&As[sm][sr * 32 + (s ^ sxor) * 8] = v;
            }
        }
        __syncthreads();

        bf16x8v afh[4], afl[4];
        #pragma unroll
        for (int mf = 0; mf < 4; ++mf) {
            int row = wm * 64 + mf * 16 + fr;
            int addr = row * 32 + ((fc ^ axor) * 8);
            afh[mf] = *(const bf16x8v*)&As[0][addr];
            afl[mf] = *(const bf16x8v*)&As[1][addr];
        }
        #pragma unroll
        for (int nf = 0; nf < 4; ++nf) {
            int col = colBase + wn * 64 + nf * 16 + fr;
            size_t boff = (size_t)col * 256 + k0 + fc * 8;
            bf16x8v bfh = *(const bf16x8v*)(BTh + boff);
            bf16x8v bfl = *(const bf16x8v*)(BTl + boff);
            #pragma unroll
            for (int mf = 0; mf < 4; ++mf) {
                acc[mf][nf] = __builtin_amdgcn_mfma_f32_16x16x32_bf16(
                                  afh[mf], bfh, acc[mf][nf], 0, 0, 0);
                acc[mf][nf] = __builtin_amdgcn_mfma_f32_16x16x32_bf16(
                                  afh[mf], bfl, acc[mf][nf], 0, 0, 0);
                acc[mf][nf] = __builtin_amdgcn_mfma_f32_16x16x32_bf16(
                                  afl[mf], bfh, acc[mf][nf], 0, 0, 0);
            }
        }
    }

    // C/D layout (m89-verified): col = lane&15, row = (lane>>4)*4 + reg
    #pragma unroll
    for (int mf = 0; mf < 4; ++mf) {
        #pragma unroll
        for (int nf = 0; nf < 4; ++nf) {
            int col = colBase + wn * 64 + nf * 16 + fr;
            #pragma unroll
            for (int r = 0; r < 4; ++r) {
                int row = rowBase + wm * 64 + mf * 16 + fc * 4 + r;
                if (row < M) C[(size_t)row * ldc + col] = acc[mf][nf][r];
            }
        }
    }
}

// ---------------------------------------------------------------------------
// combine1: h = relu( segmean(t1) + r1 + b1 ), output split to bf16 hi/lo.
// g1:[N,512] f32 = [t1 | r1]. One wave per node, float4 (4 chans) per lane.
// ---------------------------------------------------------------------------
__global__ void combine1_kernel(const float* __restrict__ g1,
                                const int* __restrict__ offs,
                                const int* __restrict__ ssrc,
                                const float* __restrict__ b1,
                                ushort* __restrict__ hh, ushort* __restrict__ hl,
                                int n) {
    int gtid = blockIdx.x * blockDim.x + threadIdx.x;
    int node = gtid >> 6;
    int lane = gtid & 63;
    if (node >= n) return;
    int beg = offs[node];
    int end = offs[node + 1];
    const float4* g = (const float4*)g1;     // row stride = 128 float4
    float4 s = make_float4(0.f, 0.f, 0.f, 0.f);
    int e = beg;
    for (; e + 1 < end; e += 2) {
        int s0 = ssrc[e];
        int s1 = ssrc[e + 1];
        float4 v0 = g[(size_t)s0 * 128 + lane];
        float4 v1 = g[(size_t)s1 * 128 + lane];
        s.x += v0.x + v1.x; s.y += v0.y + v1.y;
        s.z += v0.z + v1.z; s.w += v0.w + v1.w;
    }
    if (e < end) {
        float4 v0 = g[(size_t)ssrc[e] * 128 + lane];
        s.x += v0.x; s.y += v0.y; s.z += v0.z; s.w += v0.w;
    }
    int deg = end - beg;
    float inv = 1.0f / (float)(deg > 0 ? deg : 1);
    float4 r = g[(size_t)node * 128 + 64 + lane];
    float4 bb = ((const float4*)b1)[lane];
    float o0 = s.x * inv + r.x + bb.x;
    float o1 = s.y * inv + r.y + bb.y;
    float o2 = s.z * inv + r.z + bb.z;
    float o3 = s.w * inv + r.w + bb.w;
    o0 = o0 > 0.f ? o0 : 0.f;
    o1 = o1 > 0.f ? o1 : 0.f;
    o2 = o2 > 0.f ? o2 : 0.f;
    o3 = o3 > 0.f ? o3 : 0.f;
    ushort4 h, l;
    h.x = f2bf(o0); l.x = f2bf(o0 - bf2f(h.x));
    h.y = f2bf(o1); l.y = f2bf(o1 - bf2f(h.y));
    h.z = f2bf(o2); l.z = f2bf(o2 - bf2f(h.z));
    h.w = f2bf(o3); l.w = f2bf(o3 - bf2f(h.w));
    ((ushort4*)hh)[(size_t)node * 64 + lane] = h;
    ((ushort4*)hl)[(size_t)node * 64 + lane] = l;
}

// ---------------------------------------------------------------------------
// combine2: emb[i][c] = segmean(t2)[i][c] + r2[i][c] + b2[c]
// g2:[N,128] f32 = [t2 | r2]. One wave per node, scalar lane per channel.
// ---------------------------------------------------------------------------
__global__ void combine2_kernel(const float* __restrict__ g2,
                                const int* __restrict__ offs,
                                const int* __restrict__ ssrc,
                                const float* __restrict__ b2,
                                float* __restrict__ emb, int n) {
    int gtid = blockIdx.x * blockDim.x + threadIdx.x;
    int node = gtid >> 6;
    int lane = gtid & 63;
    if (node >= n) return;
    int beg = offs[node];
    int end = offs[node + 1];
    float s = 0.f;
    int e = beg;
    for (; e + 1 < end; e += 2) {
        int s0 = ssrc[e];
        int s1 = ssrc[e + 1];
        float v0 = g2[(size_t)s0 * 128 + lane];
        float v1 = g2[(size_t)s1 * 128 + lane];
        s += v0 + v1;
    }
    if (e < end) s += g2[(size_t)ssrc[e] * 128 + lane];
    int deg = end - beg;
    float inv = 1.0f / (float)(deg > 0 ? deg : 1);
    emb[(size_t)node * 64 + lane] =
        s * inv + g2[(size_t)node * 128 + 64 + lane] + b2[lane];
}

// ---------------------------------------------------------------------------
// Head: out[i] = sigmoid( dot(emb_u[i], W[0:64]) + dot(emb_i[i], W[64:128]) + b )
// ---------------------------------------------------------------------------
__global__ void head_kernel(const float* __restrict__ eu, const float* __restrict__ ei,
                            const float* __restrict__ hW, const float* __restrict__ hb,
                            float* __restrict__ out, int n) {
    __shared__ float w[128];
    __shared__ float b0;
    if (threadIdx.x < 128) w[threadIdx.x] = hW[threadIdx.x];
    if (threadIdx.x == 0) b0 = hb[0];
    __syncthreads();
    int i = blockIdx.x * blockDim.x + threadIdx.x;
    if (i >= n) return;
    const float4* a = (const float4*)(eu + (size_t)i * 64);
    const float4* c = (const float4*)(ei + (size_t)i * 64);
    float s = b0;
    #pragma unroll
    for (int j = 0; j < 16; ++j) {
        float4 v = a[j];
        s += v.x * w[j * 4 + 0] + v.y * w[j * 4 + 1] + v.z * w[j * 4 + 2] + v.w * w[j * 4 + 3];
    }
    #pragma unroll
    for (int j = 0; j < 16; ++j) {
        float4 v = c[j];
        s += v.x * w[64 + j * 4 + 0] + v.y * w[64 + j * 4 + 1] + v.z * w[64 + j * 4 + 2] + v.w * w[64 + j * 4 + 3];
    }
    out[i] = 1.0f / (1.0f + __expf(-s));
}

// ---------------------------------------------------------------------------
extern "C" void kernel_launch(void* const* d_in, const int* in_sizes, int n_in,
                              void* d_out, int out_size, void* d_ws, size_t ws_size,
                              hipStream_t stream) {
    const float* user_x = (const float*)d_in[0];
    const float* item_x = (const float*)d_in[1];
    const int*   u_ei   = (const int*)d_in[2];
    const int*   i_ei   = (const int*)d_in[3];
    const float* u1_Wn = (const float*)d_in[4];
    const float* u1_Wr = (const float*)d_in[5];
    const float* u1_b  = (const float*)d_in[6];
    const float* u2_Wn = (const float*)d_in[7];
    const float* u2_Wr = (const float*)d_in[8];
    const float* u2_b  = (const float*)d_in[9];
    const float* i1_Wn = (const float*)d_in[10];
    const float* i1_Wr = (const float*)d_in[11];
    const float* i1_b  = (const float*)d_in[12];
    const float* i2_Wn = (const float*)d_in[13];
    const float* i2_Wr = (const float*)d_in[14];
    const float* i2_b  = (const float*)d_in[15];
    const float* head_W = (const float*)d_in[16];
    const float* head_b = (const float*)d_in[17];
    float* out = (float*)d_out;

    // Workspace carve-up (256B aligned). Total ~240 MB.
    char* p = (char*)d_ws;
    auto alloc = [&](size_t bytes) -> void* {
        void* r = (void*)p;
        p += (bytes + 255) & ~(size_t)255;
        return r;
    };
    int* cnt_u  = (int*)alloc((size_t)N_NODES * 4);
    int* cnt_i  = (int*)alloc((size_t)N_NODES * 4);
    int* offs_u = (int*)alloc((size_t)(N_NODES + 1) * 4);
    int* offs_i = (int*)alloc((size_t)(N_NODES + 1) * 4);
    int* cur_u  = (int*)alloc((size_t)N_NODES * 4);
    int* cur_i  = (int*)alloc((size_t)N_NODES * 4);
    int* ssrc_u = (int*)alloc((size_t)N_EDGES * 4);
    int* ssrc_i = (int*)alloc((size_t)N_EDGES * 4);
    ushort* xh  = (ushort*)alloc((size_t)N_NODES * 256 * 2);   // A hi (x or reused)
    ushort* xl  = (ushort*)alloc((size_t)N_NODES * 256 * 2);   // A lo
    ushort* hh  = (ushort*)alloc((size_t)N_NODES * 256 * 2);   // h hi
    ushort* hl  = (ushort*)alloc((size_t)N_NODES * 256 * 2);   // h lo
    ushort* w1h = (ushort*)alloc((size_t)512 * 256 * 2);       // layer1 BT hi
    ushort* w1l = (ushort*)alloc((size_t)512 * 256 * 2);
    ushort* w2h = (ushort*)alloc((size_t)128 * 256 * 2);       // layer2 BT hi
    ushort* w2l = (ushort*)alloc((size_t)128 * 256 * 2);
    float* g1    = (float*)alloc((size_t)N_NODES * 512 * 4);   // [t1 | r1]
    float* g2    = g1;                                         // alias (g1 dead when g2 live)
    float* emb_u = (float*)alloc((size_t)N_NODES * EMB * 4);
    float* emb_i = (float*)alloc((size_t)N_NODES * EMB * 4);

    hipMemsetAsync(cnt_u, 0, (size_t)N_NODES * 4, stream);
    hipMemsetAsync(cnt_i, 0, (size_t)N_NODES * 4, stream);

    const int* u_src = u_ei;
    const int* u_dst = u_ei + N_EDGES;
    const int* i_src = i_ei;
    const int* i_dst = i_ei + N_EDGES;

    int egrid = (N_EDGES + 255) / 256;
    int sgrid = (N_NODES * 64 + 255) / 256;        // one wave per node
    int mgrid128 = (N_NODES + 127) / 128;          // 391
    int cvt_x_grid = (N_NODES * 256 / 4 + 255) / 256;

    // --- CSR build, both graphs ---
    hist_kernel<<<egrid, 256, 0, stream>>>(u_dst, cnt_u, N_EDGES);
    hist_kernel<<<egrid, 256, 0, stream>>>(i_dst, cnt_i, N_EDGES);
    scan_kernel<<<1, 1024, 0, stream>>>(cnt_u, offs_u, cur_u, N_NODES);
    scan_kernel<<<1, 1024, 0, stream>>>(cnt_i, offs_i, cur_i, N_NODES);
    fill_kernel<<<egrid, 256, 0, stream>>>(u_src, u_dst, cur_u, ssrc_u, N_EDGES);
    fill_kernel<<<egrid, 256, 0, stream>>>(i_src, i_dst, cur_i, ssrc_i, N_EDGES);

    // --- user encoder ---
    cvt_split<<<cvt_x_grid, 256, 0, stream>>>(user_x, xh, xl, N_NODES * 256 / 4);
    cvt_wT<<<(2 * 256 * 256 + 255) / 256, 256, 0, stream>>>(u1_Wn, u1_Wr, w1h, w1l, 256);
    cvt_wT<<<(2 * 64 * 256 + 255) / 256, 256, 0, stream>>>(u2_Wn, u2_Wr, w2h, w2l, 64);
    {
        dim3 g(mgrid128, 4);   // Nout = 512
        gemm_bf16x3<<<g, 256, 0, stream>>>(xh, xl, w1h, w1l, g1, N_NODES, 512);
    }
    combine1_kernel<<<sgrid, 256, 0, stream>>>(g1, offs_u, ssrc_u, u1_b, hh, hl, N_NODES);
    {
        dim3 g(mgrid128, 1);   // Nout = 128
        gemm_bf16x3<<<g, 256, 0, stream>>>(hh, hl, w2h, w2l, g2, N_NODES, 128);
    }
    combine2_kernel<<<sgrid, 256, 0, stream>>>(g2, offs_u, ssrc_u, u2_b, emb_u, N_NODES);

    // --- item encoder (reuse xh/xl, w buffers) ---
    cvt_split<<<cvt_x_grid, 256, 0, stream>>>(item_x, xh, xl, N_NODES * 256 / 4);
    cvt_wT<<<(2 * 256 * 256 + 255) / 256, 256, 0, stream>>>(i1_Wn, i1_Wr, w1h, w1l, 256);
    cvt_wT<<<(2 * 64 * 256 + 255) / 256, 256, 0, stream>>>(i2_Wn, i2_Wr, w2h, w2l, 64);
    {
        dim3 g(mgrid128, 4);
        gemm_bf16x3<<<g, 256, 0, stream>>>(xh, xl, w1h, w1l, g1, N_NODES, 512);
    }
    combine1_kernel<<<sgrid, 256, 0, stream>>>(g1, offs_i, ssrc_i, i1_b, hh, hl, N_NODES);
    {
        dim3 g(mgrid128, 1);
        gemm_bf16x3<<<g, 256, 0, stream>>>(hh, hl, w2h, w2l, g2, N_NODES, 128);
    }
    combine2_kernel<<<sgrid, 256, 0, stream>>>(g2, offs_i, ssrc_i, i2_b, emb_i, N_NODES);

    // --- scoring head ---
    head_kernel<<<(N_NODES + 255) / 256, 256, 0, stream>>>(emb_u, emb_i, head_W,
                                                           head_b, out, N_NODES);
}

// Round 13
// 892.592 us; speedup vs baseline: 1.5810x; 1.2900x over previous
//
#include <hip/hip_runtime.h>
#include <cstdint>
#include <cstddef>

#define N_NODES 50000
#define N_EDGES 800000
#define IN_DIM 256
#define HID 256
#define EMB 64
#define SCAN_B 1024
#define NBLK ((N_NODES + SCAN_B - 1) / SCAN_B)   // 49

typedef __attribute__((ext_vector_type(8))) short bf16x8v;   // 8 bf16 in 4 VGPRs
typedef __attribute__((ext_vector_type(4))) float f32x4v;    // MFMA accumulator

// ---- manual bf16 RNE convert ------------------------------------------------
__device__ inline ushort f2bf(float f) {
    uint32_t u = __float_as_uint(f);
    uint32_t r = (u + 0x7FFFu + ((u >> 16) & 1u)) >> 16;
    return (ushort)r;
}
__device__ inline float bf2f(ushort b) {
    return __uint_as_float((uint32_t)b << 16);
}

// ---------------------------------------------------------------------------
// CSR build: histogram -> hierarchical exclusive scan -> fill sorted src list
// ---------------------------------------------------------------------------
__global__ void hist_kernel(const int* __restrict__ dst, int* __restrict__ cnt, int E) {
    int e = blockIdx.x * blockDim.x + threadIdx.x;
    if (e < E) atomicAdd(&cnt[dst[e]], 1);
}

// local scan: per-block exclusive scan into loc (=cursor buffer), block sums out
__global__ void scan_local(const int* __restrict__ cnt, int* __restrict__ loc,
                           int* __restrict__ bsum, int n) {
    __shared__ int buf[SCAN_B];
    int tid = threadIdx.x;
    int i = blockIdx.x * SCAN_B + tid;
    int v = (i < n) ? cnt[i] : 0;
    buf[tid] = v;
    __syncthreads();
    #pragma unroll
    for (int off = 1; off < SCAN_B; off <<= 1) {
        int t = (tid >= off) ? buf[tid - off] : 0;
        __syncthreads();
        buf[tid] += t;
        __syncthreads();
    }
    if (i < n) loc[i] = buf[tid] - v;
    if (tid == SCAN_B - 1) bsum[blockIdx.x] = buf[SCAN_B - 1];
}

// scan 49 block sums in one wave-sized block; write grand total to *total_out
__global__ void scan_bsum(int* __restrict__ bsum, int nb, int* __restrict__ total_out) {
    __shared__ int b[64];
    int tid = threadIdx.x;
    int v = (tid < nb) ? bsum[tid] : 0;
    b[tid] = v;
    __syncthreads();
    #pragma unroll
    for (int off = 1; off < 64; off <<= 1) {
        int t = (tid >= off) ? b[tid - off] : 0;
        __syncthreads();
        b[tid] += t;
        __syncthreads();
    }
    if (tid < nb) bsum[tid] = b[tid] - v;
    if (tid == 63) *total_out = b[63];
}

// add block offsets; produce offs and cursor (in-place over loc)
__global__ void scan_add(int* __restrict__ loc_cursor, const int* __restrict__ bsum,
                         int* __restrict__ offs, int n) {
    int i = blockIdx.x * SCAN_B + threadIdx.x;
    if (i < n) {
        int o = loc_cursor[i] + bsum[blockIdx.x];
        offs[i] = o;
        loc_cursor[i] = o;
    }
}

__global__ void fill_kernel(const int* __restrict__ src, const int* __restrict__ dst,
                            int* __restrict__ cursor, int* __restrict__ ssrc, int E) {
    int e = blockIdx.x * blockDim.x + threadIdx.x;
    if (e < E) {
        int d = dst[e];
        int pos = atomicAdd(&cursor[d], 1);
        ssrc[pos] = src[e];
    }
}

// ---------------------------------------------------------------------------
// cvt_split: f32 [n] -> bf16 hi + bf16 lo (residual). One thread per 4 elems.
// ---------------------------------------------------------------------------
__global__ void cvt_split(const float* __restrict__ x, ushort* __restrict__ xh,
                          ushort* __restrict__ xl, int n4) {
    int i = blockIdx.x * blockDim.x + threadIdx.x;
    if (i >= n4) return;
    float4 v = ((const float4*)x)[i];
    ushort4 h, l;
    h.x = f2bf(v.x); l.x = f2bf(v.x - bf2f(h.x));
    h.y = f2bf(v.y); l.y = f2bf(v.y - bf2f(h.y));
    h.z = f2bf(v.z); l.z = f2bf(v.z - bf2f(h.z));
    h.w = f2bf(v.w); l.w = f2bf(v.w - bf2f(h.w));
    ((ushort4*)xh)[i] = h;
    ((ushort4*)xl)[i] = l;
}

// ---------------------------------------------------------------------------
// cvt_wT: build transposed+split weight BT[n][k] (k=256) from B1,B2 [256,Nhalf]
// ---------------------------------------------------------------------------
__global__ void cvt_wT(const float* __restrict__ B1, const float* __restrict__ B2,
                       ushort* __restrict__ th, ushort* __restrict__ tl, int Nhalf) {
    int idx = blockIdx.x * blockDim.x + threadIdx.x;   // n*256 + k
    if (idx >= 2 * Nhalf * 256) return;
    int nn = idx >> 8;
    int k  = idx & 255;
    const float* Bp = (nn < Nhalf) ? B1 : B2;
    int col = (nn < Nhalf) ? nn : nn - Nhalf;
    float v = Bp[(size_t)k * Nhalf + col];
    ushort h = f2bf(v);
    th[idx] = h;
    tl[idx] = f2bf(v - bf2f(h));
}

// ---------------------------------------------------------------------------
// bf16x3 split MFMA GEMM with split epilogue:
//   cols <  nsplit  -> Cb (bf16, ld = nsplit)        [neighbor term, gathered later]
//   cols >= nsplit  -> Cf (f32,  ld = ldf)           [root term, read once]
//   A   = Ah + Al : [M,256] bf16 row-major (hi/lo split of fp32 A)
//   BT  = BTh/BTl : [Ntot,256] bf16 row-major (transposed split weights)
//   Block tile 128x128, 4 waves (2x2), each wave 64x64 = 4x4 frags,
//   mfma_f32_16x16x32_bf16 x3 (hh, hl, lh). A staged in LDS, XOR-swizzled.
// ---------------------------------------------------------------------------
__global__ __launch_bounds__(256) void gemm_bf16x3(
        const ushort* __restrict__ Ah, const ushort* __restrict__ Al,
        const ushort* __restrict__ BTh, const ushort* __restrict__ BTl,
        ushort* __restrict__ Cb, float* __restrict__ Cf,
        int M, int nsplit, int ldf) {
    __shared__ ushort As[2][128 * 32];   // [hi/lo][row*32 + k], 16 KiB

    int tid  = threadIdx.x;
    int lane = tid & 63;
    int wv   = tid >> 6;        // 0..3
    int wm   = wv >> 1;         // wave row
    int wn   = wv & 1;          // wave col
    int rowBase = blockIdx.x * 128;
    int colBase = blockIdx.y * 128;

    int sr = tid & 127;
    int sm = tid >> 7;
    const ushort* Ag = sm ? Al : Ah;
    int grow = rowBase + sr;
    bool rok = grow < M;
    int sxor = (sr >> 1) & 3;

    int fr = lane & 15;         // A row-in-frag / B col / C col
    int fc = lane >> 4;         // k-slot (8 elems) / C row group
    int axor = (fr >> 1) & 3;

    f32x4v zero4 = {0.f, 0.f, 0.f, 0.f};
    f32x4v acc[4][4];
    #pragma unroll
    for (int a = 0; a < 4; ++a)
        #pragma unroll
        for (int b = 0; b < 4; ++b) acc[a][b] = zero4;

    for (int k0 = 0; k0 < 256; k0 += 32) {
        __syncthreads();
        {
            const ushort* gs = Ag + (size_t)grow * 256 + k0;
            #pragma unroll
            for (int s = 0; s < 4; ++s) {
                uint4 v = rok ? *(const uint4*)(gs + s * 8) : make_uint4(0u, 0u, 0u, 0u);
                *(uint4*)&As[sm][sr * 32 + (s ^ sxor) * 8] = v;
            }
        }
        __syncthreads();

        bf16x8v afh[4], afl[4];
        #pragma unroll
        for (int mf = 0; mf < 4; ++mf) {
            int row = wm * 64 + mf * 16 + fr;
            int addr = row * 32 + ((fc ^ axor) * 8);
            afh[mf] = *(const bf16x8v*)&As[0][addr];
            afl[mf] = *(const bf16x8v*)&As[1][addr];
        }
        #pragma unroll
        for (int nf = 0; nf < 4; ++nf) {
            int col = colBase + wn * 64 + nf * 16 + fr;
            size_t boff = (size_t)col * 256 + k0 + fc * 8;
            bf16x8v bfh = *(const bf16x8v*)(BTh + boff);
            bf16x8v bfl = *(const bf16x8v*)(BTl + boff);
            #pragma unroll
            for (int mf = 0; mf < 4; ++mf) {
                acc[mf][nf] = __builtin_amdgcn_mfma_f32_16x16x32_bf16(
                                  afh[mf], bfh, acc[mf][nf], 0, 0, 0);
                acc[mf][nf] = __builtin_amdgcn_mfma_f32_16x16x32_bf16(
                                  afh[mf], bfl, acc[mf][nf], 0, 0, 0);
                acc[mf][nf] = __builtin_amdgcn_mfma_f32_16x16x32_bf16(
                                  afl[mf], bfh, acc[mf][nf], 0, 0, 0);
            }
        }
    }

    // C/D layout (m89-verified): col = lane&15, row = (lane>>4)*4 + reg
    #pragma unroll
    for (int mf = 0; mf < 4; ++mf) {
        #pragma unroll
        for (int nf = 0; nf < 4; ++nf) {
            int col = colBase + wn * 64 + nf * 16 + fr;
            #pragma unroll
            for (int r = 0; r < 4; ++r) {
                int row = rowBase + wm * 64 + mf * 16 + fc * 4 + r;
                if (row < M) {
                    float v = acc[mf][nf][r];
                    if (col < nsplit)
                        Cb[(size_t)row * nsplit + col] = f2bf(v);
                    else
                        Cf[(size_t)row * ldf + (col - nsplit)] = v;
                }
            }
        }
    }
}

// ---------------------------------------------------------------------------
// combine1: h = relu( segmean(t1b) + r1 + b1 ), output split to bf16 hi/lo.
// t1b: [N,256] bf16 (gathered), r1: [N,256] f32 (read once). Wave per node,
// 4 channels per lane (ushort4 = 8B gather per lane), 2-deep unroll.
// ---------------------------------------------------------------------------
__global__ void combine1_kernel(const ushort* __restrict__ t1b,
                                const float* __restrict__ r1,
                                const int* __restrict__ offs,
                                const int* __restrict__ ssrc,
                                const float* __restrict__ b1,
                                ushort* __restrict__ hh, ushort* __restrict__ hl,
                                int n) {
    int gtid = blockIdx.x * blockDim.x + threadIdx.x;
    int node = gtid >> 6;
    int lane = gtid & 63;
    if (node >= n) return;
    int beg = offs[node];
    int end = offs[node + 1];
    const ushort4* t = (const ushort4*)t1b;   // row stride = 64 ushort4
    float4 s = make_float4(0.f, 0.f, 0.f, 0.f);
    int e = beg;
    for (; e + 1 < end; e += 2) {
        int s0 = ssrc[e];
        int s1 = ssrc[e + 1];
        ushort4 q0 = t[(size_t)s0 * 64 + lane];
        ushort4 q1 = t[(size_t)s1 * 64 + lane];
        s.x += bf2f(q0.x) + bf2f(q1.x);
        s.y += bf2f(q0.y) + bf2f(q1.y);
        s.z += bf2f(q0.z) + bf2f(q1.z);
        s.w += bf2f(q0.w) + bf2f(q1.w);
    }
    if (e < end) {
        ushort4 q0 = t[(size_t)ssrc[e] * 64 + lane];
        s.x += bf2f(q0.x); s.y += bf2f(q0.y);
        s.z += bf2f(q0.z); s.w += bf2f(q0.w);
    }
    int deg = end - beg;
    float inv = 1.0f / (float)(deg > 0 ? deg : 1);
    float4 r = ((const float4*)r1)[(size_t)node * 64 + lane];
    float4 bb = ((const float4*)b1)[lane];
    float o0 = s.x * inv + r.x + bb.x;
    float o1 = s.y * inv + r.y + bb.y;
    float o2 = s.z * inv + r.z + bb.z;
    float o3 = s.w * inv + r.w + bb.w;
    o0 = o0 > 0.f ? o0 : 0.f;
    o1 = o1 > 0.f ? o1 : 0.f;
    o2 = o2 > 0.f ? o2 : 0.f;
    o3 = o3 > 0.f ? o3 : 0.f;
    ushort4 h, l;
    h.x = f2bf(o0); l.x = f2bf(o0 - bf2f(h.x));
    h.y = f2bf(o1); l.y = f2bf(o1 - bf2f(h.y));
    h.z = f2bf(o2); l.z = f2bf(o2 - bf2f(h.z));
    h.w = f2bf(o3); l.w = f2bf(o3 - bf2f(h.w));
    ((ushort4*)hh)[(size_t)node * 64 + lane] = h;
    ((ushort4*)hl)[(size_t)node * 64 + lane] = l;
}

// ---------------------------------------------------------------------------
// combine2: emb = segmean(t2b) + r2 + b2. t2b: [N,64] bf16, r2: [N,64] f32.
// Wave per node, scalar channel per lane, 2-deep unroll.
// ---------------------------------------------------------------------------
__global__ void combine2_kernel(const ushort* __restrict__ t2b,
                                const float* __restrict__ r2,
                                const int* __restrict__ offs,
                                const int* __restrict__ ssrc,
                                const float* __restrict__ b2,
                                float* __restrict__ emb, int n) {
    int gtid = blockIdx.x * blockDim.x + threadIdx.x;
    int node = gtid >> 6;
    int lane = gtid & 63;
    if (node >= n) return;
    int beg = offs[node];
    int end = offs[node + 1];
    float s = 0.f;
    int e = beg;
    for (; e + 1 < end; e += 2) {
        int s0 = ssrc[e];
        int s1 = ssrc[e + 1];
        float v0 = bf2f(t2b[(size_t)s0 * 64 + lane]);
        float v1 = bf2f(t2b[(size_t)s1 * 64 + lane]);
        s += v0 + v1;
    }
    if (e < end) s += bf2f(t2b[(size_t)ssrc[e] * 64 + lane]);
    int deg = end - beg;
    float inv = 1.0f / (float)(deg > 0 ? deg : 1);
    emb[(size_t)node * 64 + lane] =
        s * inv + r2[(size_t)node * 64 + lane] + b2[lane];
}

// ---------------------------------------------------------------------------
// Head: out[i] = sigmoid( dot(emb_u[i], W[0:64]) + dot(emb_i[i], W[64:128]) + b )
// ---------------------------------------------------------------------------
__global__ void head_kernel(const float* __restrict__ eu, const float* __restrict__ ei,
                            const float* __restrict__ hW, const float* __restrict__ hb,
                            float* __restrict__ out, int n) {
    __shared__ float w[128];
    __shared__ float b0;
    if (threadIdx.x < 128) w[threadIdx.x] = hW[threadIdx.x];
    if (threadIdx.x == 0) b0 = hb[0];
    __syncthreads();
    int i = blockIdx.x * blockDim.x + threadIdx.x;
    if (i >= n) return;
    const float4* a = (const float4*)(eu + (size_t)i * 64);
    const float4* c = (const float4*)(ei + (size_t)i * 64);
    float s = b0;
    #pragma unroll
    for (int j = 0; j < 16; ++j) {
        float4 v = a[j];
        s += v.x * w[j * 4 + 0] + v.y * w[j * 4 + 1] + v.z * w[j * 4 + 2] + v.w * w[j * 4 + 3];
    }
    #pragma unroll
    for (int j = 0; j < 16; ++j) {
        float4 v = c[j];
        s += v.x * w[64 + j * 4 + 0] + v.y * w[64 + j * 4 + 1] + v.z * w[64 + j * 4 + 2] + v.w * w[64 + j * 4 + 3];
    }
    out[i] = 1.0f / (1.0f + __expf(-s));
}

// ---------------------------------------------------------------------------
extern "C" void kernel_launch(void* const* d_in, const int* in_sizes, int n_in,
                              void* d_out, int out_size, void* d_ws, size_t ws_size,
                              hipStream_t stream) {
    const float* user_x = (const float*)d_in[0];
    const float* item_x = (const float*)d_in[1];
    const int*   u_ei   = (const int*)d_in[2];
    const int*   i_ei   = (const int*)d_in[3];
    const float* u1_Wn = (const float*)d_in[4];
    const float* u1_Wr = (const float*)d_in[5];
    const float* u1_b  = (const float*)d_in[6];
    const float* u2_Wn = (const float*)d_in[7];
    const float* u2_Wr = (const float*)d_in[8];
    const float* u2_b  = (const float*)d_in[9];
    const float* i1_Wn = (const float*)d_in[10];
    const float* i1_Wr = (const float*)d_in[11];
    const float* i1_b  = (const float*)d_in[12];
    const float* i2_Wn = (const float*)d_in[13];
    const float* i2_Wr = (const float*)d_in[14];
    const float* i2_b  = (const float*)d_in[15];
    const float* head_W = (const float*)d_in[16];
    const float* head_b = (const float*)d_in[17];
    float* out = (float*)d_out;

    // Workspace carve-up (256B aligned). Total ~231 MB.
    char* p = (char*)d_ws;
    auto alloc = [&](size_t bytes) -> void* {
        void* r = (void*)p;
        p += (bytes + 255) & ~(size_t)255;
        return r;
    };
    int* cnt_u  = (int*)alloc((size_t)N_NODES * 4);
    int* cnt_i  = (int*)alloc((size_t)N_NODES * 4);
    int* offs_u = (int*)alloc((size_t)(N_NODES + 1) * 4);
    int* offs_i = (int*)alloc((size_t)(N_NODES + 1) * 4);
    int* cur_u  = (int*)alloc((size_t)N_NODES * 4);
    int* cur_i  = (int*)alloc((size_t)N_NODES * 4);
    int* bsum_u = (int*)alloc((size_t)64 * 4);
    int* bsum_i = (int*)alloc((size_t)64 * 4);
    int* ssrc_u = (int*)alloc((size_t)N_EDGES * 4);
    int* ssrc_i = (int*)alloc((size_t)N_EDGES * 4);
    ushort* xh  = (ushort*)alloc((size_t)N_NODES * 256 * 2);
    ushort* xl  = (ushort*)alloc((size_t)N_NODES * 256 * 2);
    ushort* hh  = (ushort*)alloc((size_t)N_NODES * 256 * 2);
    ushort* hl  = (ushort*)alloc((size_t)N_NODES * 256 * 2);
    ushort* w1h = (ushort*)alloc((size_t)512 * 256 * 2);
    ushort* w1l = (ushort*)alloc((size_t)512 * 256 * 2);
    ushort* w2h = (ushort*)alloc((size_t)128 * 256 * 2);
    ushort* w2l = (ushort*)alloc((size_t)128 * 256 * 2);
    ushort* t1b = (ushort*)alloc((size_t)N_NODES * 256 * 2);  // neighbor term L1 (bf16)
    float*  r1  = (float*)alloc((size_t)N_NODES * 256 * 4);   // root term L1 (f32)
    ushort* t2b = (ushort*)alloc((size_t)N_NODES * 64 * 2);   // neighbor term L2 (bf16)
    float*  r2  = (float*)alloc((size_t)N_NODES * 64 * 4);    // root term L2 (f32)
    float* emb_u = (float*)alloc((size_t)N_NODES * EMB * 4);
    float* emb_i = (float*)alloc((size_t)N_NODES * EMB * 4);

    hipMemsetAsync(cnt_u, 0, (size_t)N_NODES * 4, stream);
    hipMemsetAsync(cnt_i, 0, (size_t)N_NODES * 4, stream);

    const int* u_src = u_ei;
    const int* u_dst = u_ei + N_EDGES;
    const int* i_src = i_ei;
    const int* i_dst = i_ei + N_EDGES;

    int egrid = (N_EDGES + 255) / 256;
    int sgrid = (N_NODES * 64 + 255) / 256;        // one wave per node
    int mgrid128 = (N_NODES + 127) / 128;          // 391
    int cvt_x_grid = (N_NODES * 256 / 4 + 255) / 256;

    // --- CSR build, both graphs (hierarchical scan) ---
    hist_kernel<<<egrid, 256, 0, stream>>>(u_dst, cnt_u, N_EDGES);
    hist_kernel<<<egrid, 256, 0, stream>>>(i_dst, cnt_i, N_EDGES);
    scan_local<<<NBLK, SCAN_B, 0, stream>>>(cnt_u, cur_u, bsum_u, N_NODES);
    scan_local<<<NBLK, SCAN_B, 0, stream>>>(cnt_i, cur_i, bsum_i, N_NODES);
    scan_bsum<<<1, 64, 0, stream>>>(bsum_u, NBLK, offs_u + N_NODES);
    scan_bsum<<<1, 64, 0, stream>>>(bsum_i, NBLK, offs_i + N_NODES);
    scan_add<<<NBLK, SCAN_B, 0, stream>>>(cur_u, bsum_u, offs_u, N_NODES);
    scan_add<<<NBLK, SCAN_B, 0, stream>>>(cur_i, bsum_i, offs_i, N_NODES);
    fill_kernel<<<egrid, 256, 0, stream>>>(u_src, u_dst, cur_u, ssrc_u, N_EDGES);
    fill_kernel<<<egrid, 256, 0, stream>>>(i_src, i_dst, cur_i, ssrc_i, N_EDGES);

    // --- user encoder ---
    cvt_split<<<cvt_x_grid, 256, 0, stream>>>(user_x, xh, xl, N_NODES * 256 / 4);
    cvt_wT<<<(2 * 256 * 256 + 255) / 256, 256, 0, stream>>>(u1_Wn, u1_Wr, w1h, w1l, 256);
    cvt_wT<<<(2 * 64 * 256 + 255) / 256, 256, 0, stream>>>(u2_Wn, u2_Wr, w2h, w2l, 64);
    {
        dim3 g(mgrid128, 4);   // cols 0..255 -> t1b (bf16), 256..511 -> r1 (f32)
        gemm_bf16x3<<<g, 256, 0, stream>>>(xh, xl, w1h, w1l, t1b, r1, N_NODES, 256, 256);
    }
    combine1_kernel<<<sgrid, 256, 0, stream>>>(t1b, r1, offs_u, ssrc_u, u1_b, hh, hl, N_NODES);
    {
        dim3 g(mgrid128, 1);   // cols 0..63 -> t2b (bf16), 64..127 -> r2 (f32)
        gemm_bf16x3<<<g, 256, 0, stream>>>(hh, hl, w2h, w2l, t2b, r2, N_NODES, 64, 64);
    }
    combine2_kernel<<<sgrid, 256, 0, stream>>>(t2b, r2, offs_u, ssrc_u, u2_b, emb_u, N_NODES);

    // --- item encoder (reuse buffers) ---
    cvt_split<<<cvt_x_grid, 256, 0, stream>>>(item_x, xh, xl, N_NODES * 256 / 4);
    cvt_wT<<<(2 * 256 * 256 + 255) / 256, 256, 0, stream>>>(i1_Wn, i1_Wr, w1h, w1l, 256);
    cvt_wT<<<(2 * 64 * 256 + 255) / 256, 256, 0, stream>>>(i2_Wn, i2_Wr, w2h, w2l, 64);
    {
        dim3 g(mgrid128, 4);
        gemm_bf16x3<<<g, 256, 0, stream>>>(xh, xl, w1h, w1l, t1b, r1, N_NODES, 256, 256);
    }
    combine1_kernel<<<sgrid, 256, 0, stream>>>(t1b, r1, offs_i, ssrc_i, i1_b, hh, hl, N_NODES);
    {
        dim3 g(mgrid128, 1);
        gemm_bf16x3<<<g, 256, 0, stream>>>(hh, hl, w2h, w2l, t2b, r2, N_NODES, 64, 64);
    }
    combine2_kernel<<<sgrid, 256, 0, stream>>>(t2b, r2, offs_i, ssrc_i, i2_b, emb_i, N_NODES);

    // --- scoring head ---
    head_kernel<<<(N_NODES + 255) / 256, 256, 0, stream>>>(emb_u, emb_i, head_W,
                                                           head_b, out, N_NODES);
}